// Round 1
// baseline (425.701 us; speedup 1.0000x reference)
//
#include <hip/hip_runtime.h>
#include <hip/hip_bf16.h>
#include <stdint.h>

typedef __bf16 bf16;
typedef __bf16 bf16x8 __attribute__((ext_vector_type(8)));
typedef __bf16 bf16x4 __attribute__((ext_vector_type(4)));
typedef float f32x4 __attribute__((ext_vector_type(4)));

#define GLOAD_LDS16(gptr, lptr)                                                        \
  __builtin_amdgcn_global_load_lds((const __attribute__((address_space(1))) void*)(gptr), \
                                   (__attribute__((address_space(3))) void*)(lptr), 16, 0, 0)

// ---------------- weight cast fp32 -> bf16 ----------------
__global__ __launch_bounds__(256) void cast_f2b(const float* __restrict__ in,
                                                bf16* __restrict__ out, int n) {
  int i = (blockIdx.x * 256 + threadIdx.x) * 4;
  if (i >= n) return;
  const float4 v = *(const float4*)(in + i);
  bf16x4 o;
  o[0] = (bf16)v.x; o[1] = (bf16)v.y; o[2] = (bf16)v.z; o[3] = (bf16)v.w;
  *(bf16x4*)(out + i) = o;
}

// ---------------- prep: cast+transpose x -> xbT[n][c], 2x2 maxpool -> pxT[m][c] ----
// One batch per launch. grid = 32(ct) x 32(h0) = 1024 blocks, 256 threads.
// Covers c in [ct*32,+32), spatial rows h=2*h0, 2*h0+1 (n = h0*128 .. +128).
__global__ __launch_bounds__(256) void prep_kernel(const float* __restrict__ x,
                                                   bf16* __restrict__ xbT,
                                                   bf16* __restrict__ pxT) {
  const int bid = blockIdx.x;
  const int h0 = bid & 31, ct = bid >> 5;
  const int tid = threadIdx.x;
  __shared__ float tile[32][129];
  const float* xs = x + (size_t)(ct * 32) * 4096 + h0 * 128;
#pragma unroll
  for (int e = 0; e < 16; ++e) {
    int idx = e * 256 + tid;
    int c = idx >> 7, n = idx & 127;
    tile[c][n] = xs[(size_t)c * 4096 + n];
  }
  __syncthreads();
  bf16* xo = xbT + (size_t)(h0 * 128) * 1024 + ct * 32;
#pragma unroll
  for (int e = 0; e < 16; ++e) {
    int idx = e * 256 + tid;
    int n = idx >> 5, c = idx & 31;
    xo[(size_t)n * 1024 + c] = (bf16)tile[c][n];
  }
  bf16* po = pxT + (size_t)(h0 * 32) * 1024 + ct * 32;
#pragma unroll
  for (int e = 0; e < 4; ++e) {
    int idx = e * 256 + tid;
    int m = idx >> 5, c = idx & 31;
    float v = fmaxf(fmaxf(tile[c][2 * m], tile[c][2 * m + 1]),
                    fmaxf(tile[c][64 + 2 * m], tile[c][64 + 2 * m + 1]));
    po[(size_t)m * 1024 + c] = (bf16)v;
  }
}

// ---------------- bt-flavor GEMM: C[MxN] = A[MxK] * B[NxK]^T ----------------
// EPI: 0 bf16 store; 1 bf16 + bias[col]; 2 bf16 + bias[row];
//      3 fp32 store * scale; 4 fp32 store + bias[row] + resid
template <int EPI>
__global__ __launch_bounds__(256) void gemm_bt(
    const bf16* __restrict__ A, long long sA, int lda,
    const bf16* __restrict__ B, long long sB, int ldb,
    void* __restrict__ Cv, long long sC, int ldc, int K,
    const float* __restrict__ bias,
    const float* __restrict__ resid, long long sResid, float scale) {
  const int z = blockIdx.z;
  A += (size_t)z * sA;
  B += (size_t)z * sB;
  const int tid = threadIdx.x;
  const int w = tid >> 6, lane = tid & 63;
  const int r16 = lane & 15, half = lane >> 4;
  const long long tileM = (long long)blockIdx.x * 128;
  const long long tileN = (long long)blockIdx.y * 128;

  __shared__ bf16 As[2][128 * 32];
  __shared__ bf16 Bs[2][128 * 32];

  f32x4 acc[4][4] = {};

  const int srow = tid >> 2;
  const int soff = (tid & 3) * 16;
  const char* Ag0 = (const char*)A + ((size_t)(tileM + srow) * lda) * 2 + soff;
  const char* Bg0 = (const char*)B + ((size_t)(tileN + srow) * ldb) * 2 + soff;
  const size_t arow64 = (size_t)64 * lda * 2;
  const size_t brow64 = (size_t)64 * ldb * 2;

  auto stage = [&](int buf, int k0) {
    const char* a = Ag0 + (size_t)k0 * 2;
    const char* b = Bg0 + (size_t)k0 * 2;
    bf16* al = &As[buf][w * 512];
    bf16* bl = &Bs[buf][w * 512];
    GLOAD_LDS16(a, al);
    GLOAD_LDS16(a + arow64, al + 2048);
    GLOAD_LDS16(b, bl);
    GLOAD_LDS16(b + brow64, bl + 2048);
  };

  const int wr = (w >> 1) * 64, wc = (w & 1) * 64;
  const int nt = K >> 5;
  stage(0, 0);
  __syncthreads();
  int cur = 0;
  for (int t = 0; t < nt; ++t) {
    if (t + 1 < nt) stage(cur ^ 1, (t + 1) * 32);
    bf16x8 af[4], bfv[4];
#pragma unroll
    for (int f = 0; f < 4; ++f) {
      af[f]  = *(const bf16x8*)&As[cur][(wr + f * 16 + r16) * 32 + half * 8];
      bfv[f] = *(const bf16x8*)&Bs[cur][(wc + f * 16 + r16) * 32 + half * 8];
    }
#pragma unroll
    for (int i = 0; i < 4; ++i)
#pragma unroll
      for (int j = 0; j < 4; ++j)
        acc[i][j] = __builtin_amdgcn_mfma_f32_16x16x32_bf16(af[i], bfv[j], acc[i][j], 0, 0, 0);
    __syncthreads();
    cur ^= 1;
  }

  if constexpr (EPI == 3 || EPI == 4) {
    float* C = (float*)Cv + (size_t)z * sC;
#pragma unroll
    for (int i = 0; i < 4; ++i) {
      const int row0 = (int)tileM + wr + i * 16 + half * 4;
#pragma unroll
      for (int j = 0; j < 4; ++j) {
        const int col = (int)tileN + wc + j * 16 + r16;
#pragma unroll
        for (int r = 0; r < 4; ++r) {
          float v = acc[i][j][r];
          if constexpr (EPI == 3) v *= scale;
          if constexpr (EPI == 4) {
            v += bias[row0 + r];
            v += resid[(size_t)z * sResid + (size_t)(row0 + r) * ldc + col];
          }
          C[(size_t)(row0 + r) * ldc + col] = v;
        }
      }
    }
  } else {
    bf16* C = (bf16*)Cv + (size_t)z * sC;
#pragma unroll
    for (int i = 0; i < 4; ++i) {
      const int row0 = (int)tileM + wr + i * 16 + half * 4;
#pragma unroll
      for (int j = 0; j < 4; ++j) {
        const int col = (int)tileN + wc + j * 16 + r16;
        float badd = 0.f;
        if constexpr (EPI == 1) badd = bias[col];
#pragma unroll
        for (int r = 0; r < 4; ++r) {
          float v = acc[i][j][r];
          if constexpr (EPI == 1) v += badd;
          if constexpr (EPI == 2) v += bias[row0 + r];
          C[(size_t)(row0 + r) * ldc + col] = (bf16)v;
        }
      }
    }
  }
}

// ---------------- row softmax over 1024 fp32 logits; write p bf16 in-place ------
// One wave per row; p row occupies first 2048 bytes of the 4096-byte logits row.
__global__ __launch_bounds__(256) void softmax_k(float* __restrict__ L) {
  const int row = blockIdx.x * 4 + (threadIdx.x >> 6);
  const int lane = threadIdx.x & 63;
  float* Lr = L + (size_t)row * 1024;
  float v[16];
  float m = -1e30f;
#pragma unroll
  for (int e = 0; e < 4; ++e) {
    float4 t4 = *(const float4*)(Lr + lane * 16 + e * 4);
    v[e * 4 + 0] = t4.x; v[e * 4 + 1] = t4.y;
    v[e * 4 + 2] = t4.z; v[e * 4 + 3] = t4.w;
  }
#pragma unroll
  for (int i = 0; i < 16; ++i) m = fmaxf(m, v[i]);
#pragma unroll
  for (int o = 32; o > 0; o >>= 1) m = fmaxf(m, __shfl_xor(m, o));
  float s = 0.f;
#pragma unroll
  for (int i = 0; i < 16; ++i) { v[i] = __expf(v[i] - m); s += v[i]; }
#pragma unroll
  for (int o = 32; o > 0; o >>= 1) s += __shfl_xor(s, o);
  const float inv = 1.0f / s;
  bf16* P = (bf16*)Lr;
  bf16x8 o0, o1;
#pragma unroll
  for (int i = 0; i < 8; ++i) {
    o0[i] = (bf16)(v[i] * inv);
    o1[i] = (bf16)(v[8 + i] * inv);
  }
  *(bf16x8*)(P + lane * 16) = o0;
  *(bf16x8*)(P + lane * 16 + 8) = o1;
}

// ---------------- launch ----------------
extern "C" void kernel_launch(void* const* d_in, const int* in_sizes, int n_in,
                              void* d_out, int out_size, void* d_ws, size_t ws_size,
                              hipStream_t stream) {
  const float* x  = (const float*)d_in[0];
  const float* Wt = (const float*)d_in[1];
  const float* bt = (const float*)d_in[2];
  const float* Wp = (const float*)d_in[3];
  const float* bp = (const float*)d_in[4];
  const float* Wg = (const float*)d_in[5];
  const float* bg = (const float*)d_in[6];
  const float* Wo = (const float*)d_in[7];
  const float* bo = (const float*)d_in[8];
  float* out = (float*)d_out;

  const size_t MB = 1024ull * 1024ull;
  char* ws = (char*)d_ws;
  bf16* WtB = (bf16*)(ws + 0 * MB);
  bf16* WpB = (bf16*)(ws + 1 * MB);
  bf16* WgB = (bf16*)(ws + 2 * MB);
  bf16* WoB = (bf16*)(ws + 3 * MB);

  const bool compact = ws_size < 132 * MB;
  bf16 *xbT, *pxT, *thetaT, *phiT, *gbuf;
  if (!compact) {
    xbT    = (bf16*)(ws + 4 * MB);    // 64MB: all 8 batches
    pxT    = (bf16*)(ws + 68 * MB);   // 16MB
    thetaT = (bf16*)(ws + 84 * MB);   // 32MB
    phiT   = (bf16*)(ws + 116 * MB);  // 8MB
    gbuf   = (bf16*)(ws + 124 * MB);  // 8MB -> 132MB total
  } else {
    xbT    = (bf16*)(ws + 4 * MB);    // 8MB: one batch, reused
    pxT    = (bf16*)(ws + 12 * MB);   // 16MB
    thetaT = (bf16*)(ws + 28 * MB);   // 32MB
    phiT   = (bf16*)(ws + 60 * MB);   // 8MB
    gbuf   = (bf16*)(ws + 68 * MB);   // 8MB -> 76MB total
  }
  bf16* tT = thetaT;  // thetaT dead after G4; reuse for t

  cast_f2b<<<512, 256, 0, stream>>>(Wt, WtB, 512 * 1024);
  cast_f2b<<<512, 256, 0, stream>>>(Wp, WpB, 512 * 1024);
  cast_f2b<<<512, 256, 0, stream>>>(Wg, WgB, 512 * 1024);
  cast_f2b<<<512, 256, 0, stream>>>(Wo, WoB, 1024 * 512);

  const float scale = 0.044194173824159216f;  // 512^-0.5

  if (!compact) {
    for (int b = 0; b < 8; ++b)
      prep_kernel<<<1024, 256, 0, stream>>>(x + (size_t)b * 1024 * 4096,
                                            xbT + (size_t)b * 4096 * 1024,
                                            pxT + (size_t)b * 1024 * 1024);
    // G1: thetaT[n,d] = xbT[n,c] . Wt[d,c] + b_theta[d]
    gemm_bt<1><<<dim3(32, 4, 8), 256, 0, stream>>>(xbT, 4096ll * 1024, 1024, WtB, 0, 1024,
                                                   thetaT, 4096ll * 512, 512, 1024,
                                                   bt, nullptr, 0, 1.f);
  } else {
    for (int b = 0; b < 8; ++b) {
      prep_kernel<<<1024, 256, 0, stream>>>(x + (size_t)b * 1024 * 4096, xbT,
                                            pxT + (size_t)b * 1024 * 1024);
      gemm_bt<1><<<dim3(32, 4, 1), 256, 0, stream>>>(xbT, 0, 1024, WtB, 0, 1024,
                                                     thetaT + (size_t)b * 4096 * 512, 0, 512,
                                                     1024, bt, nullptr, 0, 1.f);
    }
  }
  // G2: phiT[m,d] = pxT[m,c] . Wp[d,c] + b_phi[d]
  gemm_bt<1><<<dim3(8, 4, 8), 256, 0, stream>>>(pxT, 1024ll * 1024, 1024, WpB, 0, 1024,
                                                phiT, 1024ll * 512, 512, 1024,
                                                bp, nullptr, 0, 1.f);
  // G3: g[d,m] = Wg[d,c] . pxT[m,c] + b_g[d]
  gemm_bt<2><<<dim3(4, 8, 8), 256, 0, stream>>>(WgB, 0, 1024, pxT, 1024ll * 1024, 1024,
                                                gbuf, 512ll * 1024, 1024, 1024,
                                                bg, nullptr, 0, 1.f);
  // G4: logits[n,m] = scale * thetaT[n,d] . phiT[m,d]  -> fp32 into d_out (scratch)
  gemm_bt<3><<<dim3(32, 8, 8), 256, 0, stream>>>(thetaT, 4096ll * 512, 512,
                                                 phiT, 1024ll * 512, 512,
                                                 out, 4096ll * 1024, 1024, 512,
                                                 nullptr, nullptr, 0, scale);
  // softmax rows (32768 rows of 1024); p bf16 written in-place (ld = 2048)
  softmax_k<<<8192, 256, 0, stream>>>(out);
  // G5: tT[n,d] = p[n,m] . g[d,m]
  gemm_bt<0><<<dim3(32, 4, 8), 256, 0, stream>>>((const bf16*)out, 8388608ll, 2048,
                                                 gbuf, 512ll * 1024, 1024,
                                                 tT, 4096ll * 512, 512, 1024,
                                                 nullptr, nullptr, 0, 1.f);
  // G6: out[o,n] = Wo[o,d] . tT[n,d] + b_out[o] + x[b,o,n]
  gemm_bt<4><<<dim3(8, 32, 8), 256, 0, stream>>>(WoB, 0, 512, tT, 4096ll * 512, 512,
                                                 out, 1024ll * 4096, 4096, 512,
                                                 bo, x, 1024ll * 4096, 1.f);
}